// Round 2
// baseline (1412.989 us; speedup 1.0000x reference)
//
#include <hip/hip_runtime.h>

#define DIN 4096
#define DOUT 64
#define SEQ 2048
#define MAXL 16
#define NSLAB (DIN / 32)   // 128 K-slabs of 32 (one 16x16x32 MFMA K-step each)
#define BK 64
#define WT_STRIDE 72

typedef __bf16 bf16x8 __attribute__((ext_vector_type(8)));
typedef float f32x4 __attribute__((ext_vector_type(4)));

// ---------------------------------------------------------------------------
// FAST PATH, kernel 1 — W swizzle+convert into workspace (needs 8.39 MB ws).
//   wpre[(((aid*NSLAB + s)*4 + t)*64 + lane)*8 + j]
//     = bf16( W[aid][s*32 + (lane>>4)*8 + j][t*16 + (lane&15)] )
// Exactly the B-fragment layout the verified LDS kernel fed MFMA (same RNE
// cast), so fast-path results are bit-identical to the verified baseline.
// ---------------------------------------------------------------------------
__global__ __launch_bounds__(256)
void lora_wprep(const float* __restrict__ weight, __bf16* __restrict__ wpre)
{
    const int bid  = blockIdx.x;              // aid*NSLAB + s
    const int tid  = threadIdx.x;
    const int t    = tid >> 6;                // n-tile 0..3
    const int lane = tid & 63;
    const int aid  = bid >> 7;                // /NSLAB
    const int s    = bid & (NSLAB - 1);

    const float* src = weight
        + ((size_t)aid * DIN + s * 32 + (lane >> 4) * 8) * DOUT
        + t * 16 + (lane & 15);

    bf16x8 v;
#pragma unroll
    for (int j = 0; j < 8; ++j)
        v[j] = (__bf16)src[(size_t)j * DOUT];

    *((bf16x8*)wpre + ((size_t)bid * 4 + t) * 64 + lane) = v;  // 16B/lane coalesced
}

// ---------------------------------------------------------------------------
// FAST PATH, kernel 2 — barrier-free streaming GEMM.
// Block: 64 rows, 4 waves, wave owns 16 rows x full N=64 (4 n-tiles).
// A-frags straight from global x (m = lane&15, k = quad*8+j — verified);
// B-frags straight from wpre (16 B/lane, L2/L3-resident). No LDS, no
// __syncthreads: nothing drains vmcnt, loads pipeline freely across slabs.
// ---------------------------------------------------------------------------
__global__ __launch_bounds__(256, 4)
void lora_gemm_fast(const float* __restrict__ x,
                    const int* __restrict__ adapter_ids,
                    const __bf16* __restrict__ wpre,
                    float* __restrict__ out)
{
    const int bid  = blockIdx.x;        // 1024 blocks
    const int row0 = bid * 64;          // 64 | SEQ so whole block shares batch b
    const int b    = row0 / SEQ;
    const int aid  = adapter_ids[b];

    const int tid  = threadIdx.x;
    const int wave = tid >> 6;
    const int lane = tid & 63;
    const int m16  = lane & 15;
    const int quad = lane >> 4;

    const float*  xrow = x + (size_t)(row0 + wave * 16 + m16) * DIN + quad * 8;
    const bf16x8* wp   = (const bf16x8*)wpre + (size_t)aid * NSLAB * 4 * 64 + lane;

    f32x4 acc[4];
#pragma unroll
    for (int t = 0; t < 4; ++t) acc[t] = (f32x4)0.0f;

#pragma unroll 2
    for (int s = 0; s < NSLAB; ++s) {
        const f32x4 xa = *(const f32x4*)(xrow + s * 32);
        const f32x4 xb = *(const f32x4*)(xrow + s * 32 + 4);
        bf16x8 a;
        a[0] = (__bf16)xa[0]; a[1] = (__bf16)xa[1];
        a[2] = (__bf16)xa[2]; a[3] = (__bf16)xa[3];
        a[4] = (__bf16)xb[0]; a[5] = (__bf16)xb[1];
        a[6] = (__bf16)xb[2]; a[7] = (__bf16)xb[3];

#pragma unroll
        for (int t = 0; t < 4; ++t) {
            const bf16x8 bf = wp[(s * 4 + t) * 64];   // 1 KB/wave, coalesced, L2-hit
            acc[t] = __builtin_amdgcn_mfma_f32_16x16x32_bf16(a, bf, acc[t], 0, 0, 0);
        }
    }

    // C/D layout (verified): col = lane&15, row = quad*4 + reg
    float* obase = out + (size_t)(row0 + wave * 16 + quad * 4) * DOUT + m16;
#pragma unroll
    for (int i = 0; i < 4; ++i)
#pragma unroll
        for (int t = 0; t < 4; ++t)
            obase[(size_t)i * DOUT + t * 16] = acc[t][i];
}

// ---------------------------------------------------------------------------
// FALLBACK — the harness-verified round-0 kernel (LDS W-staging, no ws use).
// Used only when ws_size < 8.39 MB, so we can never write out of bounds.
// ---------------------------------------------------------------------------
__global__ __launch_bounds__(256, 2)
void lora_gemm_lds(const float* __restrict__ x,
                   const int* __restrict__ adapter_ids,
                   const float* __restrict__ weight,
                   float* __restrict__ out)
{
    __shared__ __align__(16) __bf16 wt[64 * WT_STRIDE];

    const int bid  = blockIdx.x;
    const int row0 = bid * 64;
    const int b    = row0 / SEQ;
    const int aid  = adapter_ids[b];
    const float* wbase = weight + (size_t)aid * DIN * DOUT;

    const int tid  = threadIdx.x;
    const int wave = tid >> 6;
    const int lane = tid & 63;
    const int m16  = lane & 15;
    const int quad = lane >> 4;

    const float* xrow = x + (size_t)(row0 + wave * 16 + m16) * DIN + quad * 8;

    f32x4 acc[4];
#pragma unroll
    for (int t = 0; t < 4; ++t) acc[t] = (f32x4)0.0f;

    const int s_kk = tid >> 4;
    const int s_n4 = tid & 15;

    for (int k0 = 0; k0 < DIN; k0 += BK) {
#pragma unroll
        for (int p = 0; p < 4; ++p) {
            const int kk = p * 16 + s_kk;
            const f32x4 w4 = *(const f32x4*)(wbase + (size_t)(k0 + kk) * DOUT + s_n4 * 4);
#pragma unroll
            for (int i = 0; i < 4; ++i)
                wt[(s_n4 * 4 + i) * WT_STRIDE + kk] = (__bf16)w4[i];
        }
        __syncthreads();

#pragma unroll
        for (int ks = 0; ks < BK; ks += 32) {
            const f32x4 xa = *(const f32x4*)(xrow + k0 + ks);
            const f32x4 xb = *(const f32x4*)(xrow + k0 + ks + 4);
            bf16x8 a;
            a[0] = (__bf16)xa[0]; a[1] = (__bf16)xa[1];
            a[2] = (__bf16)xa[2]; a[3] = (__bf16)xa[3];
            a[4] = (__bf16)xb[0]; a[5] = (__bf16)xb[1];
            a[6] = (__bf16)xb[2]; a[7] = (__bf16)xb[3];
#pragma unroll
            for (int t = 0; t < 4; ++t) {
                const bf16x8 bf = *(const bf16x8*)(&wt[(t * 16 + m16) * WT_STRIDE + ks + quad * 8]);
                acc[t] = __builtin_amdgcn_mfma_f32_16x16x32_bf16(a, bf, acc[t], 0, 0, 0);
            }
        }
        __syncthreads();
    }

    float* obase = out + (size_t)(row0 + wave * 16 + quad * 4) * DOUT + m16;
#pragma unroll
    for (int i = 0; i < 4; ++i)
#pragma unroll
        for (int t = 0; t < 4; ++t)
            obase[(size_t)i * DOUT + t * 16] = acc[t][i];
}

extern "C" void kernel_launch(void* const* d_in, const int* in_sizes, int n_in,
                              void* d_out, int out_size, void* d_ws, size_t ws_size,
                              hipStream_t stream) {
    const float* x   = (const float*)d_in[0];
    const int*   ids = (const int*)d_in[1];
    const float* w   = (const float*)d_in[2];
    float* out       = (float*)d_out;

    const int total_rows = 32 * SEQ;               // 65536
    const size_t wpre_bytes = (size_t)MAXL * DIN * DOUT * sizeof(__bf16);  // 8.39 MB

    if (d_ws != nullptr && ws_size >= wpre_bytes) {
        __bf16* wpre = (__bf16*)d_ws;
        lora_wprep<<<dim3(MAXL * NSLAB), dim3(256), 0, stream>>>(w, wpre);
        lora_gemm_fast<<<dim3(total_rows / 64), dim3(256), 0, stream>>>(x, ids, wpre, out);
    } else {
        lora_gemm_lds<<<dim3(total_rows / 64), dim3(256), 0, stream>>>(x, ids, w, out);
    }
}